// Round 12
// baseline (820.315 us; speedup 1.0000x reference)
//
#include <hip/hip_runtime.h>
#include <math.h>

// SLAYER MLP forward: spike(psp(W2 @ spike(psp(W1 @ x))))
// B=256, IN=78, HID=16, OUT=20, T=1000, K=100 (SRM alpha, tau=10)
//
// fp64 accumulation everywhere (absmax 0.0 rounds 0-11), fp32 rounding at
// reference materialization points (einsum outputs z1/z2, final u).
//
// Round-12: register-pressure surgery only (round 11 measured l2f at
// VGPR=256, occupancy 9.4%, 97.5us — allocator interleaved the pg-loop's two
// iterations and the FIR):
//  - l2f: #pragma unroll 1 on pg-loop and FIR task loop + launch_bounds
//    (256,4) -> cap 128 VGPR, 4 waves/SIMD (= LDS limit at 36.7KB)
//  - l1f: launch_bounds(256,3) (cap 168; liveness ~135, safe margin)
// All structure identical to round 11.

#define B_     256
#define IN_    78
#define HID_   16
#define OUT_   20
#define T_     1000
#define TT_    125
#define J_     224              // TT + K - 1
#define ZSTR_  228              // z LDS row stride (floats)
#define XSTR_  256              // activation LDS row stride (pow2, pad zeroed)

// ---------------- FIR building blocks (named scalars only) ----------------
#define GRP(EP, A0,A1,A2,A3, B0,B1,B2,B3, C0,C1,C2) { \
  const double2 e01_ = *(const double2*)(EP); \
  const double2 e23_ = *(const double2*)((EP)+2); \
  u0 += e01_.x*(A3); u1 += e01_.x*(B0); u2 += e01_.x*(B1); u3 += e01_.x*(B2); \
  u4 += e01_.x*(B3); u5 += e01_.x*(C0); u6 += e01_.x*(C1); u7 += e01_.x*(C2); \
  u0 += e01_.y*(A2); u1 += e01_.y*(A3); u2 += e01_.y*(B0); u3 += e01_.y*(B1); \
  u4 += e01_.y*(B2); u5 += e01_.y*(B3); u6 += e01_.y*(C0); u7 += e01_.y*(C1); \
  u0 += e23_.x*(A1); u1 += e23_.x*(A2); u2 += e23_.x*(A3); u3 += e23_.x*(B0); \
  u4 += e23_.x*(B1); u5 += e23_.x*(B2); u6 += e23_.x*(B3); u7 += e23_.x*(C0); \
  u0 += e23_.y*(A0); u1 += e23_.y*(A1); u2 += e23_.y*(A2); u3 += e23_.y*(A3); \
  u4 += e23_.y*(B0); u5 += e23_.y*(B1); u6 += e23_.y*(B2); u7 += e23_.y*(B3); }

#define LOADF(X0,X1,X2,X3, P) { \
  const float4 lf_ = *(const float4*)(P); \
  X0 = (double)lf_.x; X1 = (double)lf_.y; X2 = (double)lf_.z; X3 = (double)lf_.w; }

// Rolled FIR over one zf row; expects zrow, eps_d, u0..u7 in scope.
#define FIR_BODY(ZROW) { \
  double A0,A1,A2,A3,B0,B1,B2,B3,C0,C1,C2,C3; \
  LOADF(A0,A1,A2,A3, (ZROW) + 96); \
  LOADF(B0,B1,B2,B3, (ZROW) + 100); \
  LOADF(C0,C1,C2,C3, (ZROW) + 104); \
  GRP(eps_d, A0,A1,A2,A3, B0,B1,B2,B3, C0,C1,C2) \
  const float*  zp_ = (ZROW) + 92; \
  const double* ep_ = eps_d + 4; \
  _Pragma("unroll 1") \
  for (int k_ = 0; k_ < 8; ++k_) { \
    LOADF(C0,C1,C2,C3, zp_); \
    GRP(ep_,     C0,C1,C2,C3, A0,A1,A2,A3, B0,B1,B2) \
    LOADF(B0,B1,B2,B3, zp_ - 4); \
    GRP(ep_ + 4, B0,B1,B2,B3, C0,C1,C2,C3, A0,A1,A2) \
    LOADF(A0,A1,A2,A3, zp_ - 8); \
    GRP(ep_ + 8, A0,A1,A2,A3, B0,B1,B2,B3, C0,C1,C2) \
    zp_ -= 12; ep_ += 12; \
  } }

__device__ __forceinline__ void init_eps_d(double* eps_d, int tid) {
  if (tid < 100) {
    float a = (float)tid / 10.0f;           // identical fp32 ops to reference
    float e = a * expf(1.0f - a);
    eps_d[tid] = (double)e;                 // exact widening
  }
}

// ---------------- mm building blocks --------------------------------------
#define MMROW(XR, W0, W1) { \
  const float2 f0_ = *(const float2*)((XR)); \
  const float2 f1_ = *(const float2*)((XR) + 64); \
  const float2 f2_ = *(const float2*)((XR) + 128); \
  const float2 f3_ = *(const float2*)((XR) + 192); \
  const double x0_=(double)f0_.x, x1_=(double)f0_.y; \
  const double x2_=(double)f1_.x, x3_=(double)f1_.y; \
  const double x4_=(double)f2_.x, x5_=(double)f2_.y; \
  const double x6_=(double)f3_.x, x7_=(double)f3_.y; \
  m00 += (W0)*x0_; m01 += (W0)*x1_; m02 += (W0)*x2_; m03 += (W0)*x3_; \
  m04 += (W0)*x4_; m05 += (W0)*x5_; m06 += (W0)*x6_; m07 += (W0)*x7_; \
  m10 += (W1)*x0_; m11 += (W1)*x1_; m12 += (W1)*x2_; m13 += (W1)*x3_; \
  m14 += (W1)*x4_; m15 += (W1)*x5_; m16 += (W1)*x6_; m17 += (W1)*x7_; }

#define ZSTORE_PAIR(ZBASE0) { \
  float* z0_ = (ZBASE0); \
  float* z1_ = z0_ + ZSTR_; \
  *(float2*)(z0_)       = make_float2((float)m00, (float)m01); \
  *(float2*)(z0_ + 64)  = make_float2((float)m02, (float)m03); \
  *(float2*)(z0_ + 128) = make_float2((float)m04, (float)m05); \
  *(float2*)(z1_)       = make_float2((float)m10, (float)m11); \
  *(float2*)(z1_ + 64)  = make_float2((float)m12, (float)m13); \
  *(float2*)(z1_ + 128) = make_float2((float)m14, (float)m15); \
  if (q < 16) { \
    *(float2*)(z0_ + 192) = make_float2((float)m06, (float)m07); \
    *(float2*)(z1_ + 192) = make_float2((float)m16, (float)m17); \
  } }

// -------- l1f: s1 = spike(FIR(round32(W1 @ x))), fused per (b, tile) -------
__global__ __launch_bounds__(256, 3) void l1f(
    const float* __restrict__ x, const float* __restrict__ W1,
    float* __restrict__ sout)
{
  __shared__ float xs[13 * XSTR_];    // 13,312 B
  __shared__ float zf[HID_ * ZSTR_];  // 14,592 B
  __shared__ float wf[16 * 80];       //  5,120 B
  __shared__ __align__(16) double eps_d[100];   // total ~33.8 KB

  const int tid  = threadIdx.x;
  const int b    = blockIdx.x >> 3;
  const int tile = blockIdx.x & 7;
  const int t0   = tile * TT_;

  init_eps_d(eps_d, tid);
  for (int idx = tid; idx < HID_ * IN_; idx += 256)
    wf[(idx / IN_) * 80 + (idx % IN_)] = W1[idx];
  if (tid < HID_ * 4)                              // zero zf pad cols 224..227
    zf[(tid >> 2) * ZSTR_ + 224 + (tid & 3)] = 0.0f;

  const int  c   = tid;                // staging column 0..255
  const int  tg  = t0 - 99 + c;        // global t (max 999)
  const bool cok = (c < J_) && (tg >= 0);

  const int p = tid >> 5;
  const int q = tid & 31;

  double m00=0,m01=0,m02=0,m03=0,m04=0,m05=0,m06=0,m07=0;
  double m10=0,m11=0,m12=0,m13=0,m14=0,m15=0,m16=0,m17=0;
  float g0,g1,g2,g3,g4,g5,g6,g7,g8,g9,g10,g11,g12;

#define ISSUE_L1(CI) { \
    const float* xb_ = x + ((size_t)b * IN_ + (CI) * 13) * T_ + tg; \
    g0  = cok ? xb_[0]       : 0.0f;  g1  = cok ? xb_[T_]      : 0.0f; \
    g2  = cok ? xb_[2  * T_] : 0.0f;  g3  = cok ? xb_[3  * T_] : 0.0f; \
    g4  = cok ? xb_[4  * T_] : 0.0f;  g5  = cok ? xb_[5  * T_] : 0.0f; \
    g6  = cok ? xb_[6  * T_] : 0.0f;  g7  = cok ? xb_[7  * T_] : 0.0f; \
    g8  = cok ? xb_[8  * T_] : 0.0f;  g9  = cok ? xb_[9  * T_] : 0.0f; \
    g10 = cok ? xb_[10 * T_] : 0.0f;  g11 = cok ? xb_[11 * T_] : 0.0f; \
    g12 = cok ? xb_[12 * T_] : 0.0f; }

  ISSUE_L1(0)
#pragma unroll 1
  for (int ci = 0; ci < 6; ++ci) {
    __syncthreads();                  // all waves done reading previous chunk
    {
      float* dst = &xs[c];
      dst[0]          = g0;   dst[XSTR_]      = g1;
      dst[2  * XSTR_] = g2;   dst[3  * XSTR_] = g3;
      dst[4  * XSTR_] = g4;   dst[5  * XSTR_] = g5;
      dst[6  * XSTR_] = g6;   dst[7  * XSTR_] = g7;
      dst[8  * XSTR_] = g8;   dst[9  * XSTR_] = g9;
      dst[10 * XSTR_] = g10;  dst[11 * XSTR_] = g11;
      dst[12 * XSTR_] = g12;
    }
    __syncthreads();
    if (ci < 5) ISSUE_L1(ci + 1)      // next chunk's loads fly under compute
    const int wb0 = (2*p) * 80 + ci * 13;
    const int wb1 = wb0 + 80;
#pragma unroll
    for (int i = 0; i < 13; ++i) {
      const float* xr = &xs[i * XSTR_ + 2 * q];
      const double w0 = (double)wf[wb0 + i];
      const double w1 = (double)wf[wb1 + i];
      MMROW(xr, w0, w1)
    }
  }
  ZSTORE_PAIR(&zf[(2*p) * ZSTR_ + 2 * q])
  __syncthreads();

  { // FIR + threshold: 16 h x 16 q16 = 256 tasks exactly
    const int h = tid >> 4, q16 = tid & 15;
    const float* zrow = &zf[h * ZSTR_ + 8 * q16];
    double u0=0,u1=0,u2=0,u3=0,u4=0,u5=0,u6=0,u7=0;
    FIR_BODY(zrow)
    const size_t base = ((size_t)b * HID_ + h) * T_ + t0 + 8 * q16;
    const int tb = 8 * q16;
    const float f0=(float)u0, f1=(float)u1, f2=(float)u2, f3=(float)u3;
    const float f4=(float)u4, f5=(float)u5, f6=(float)u6, f7=(float)u7;
    sout[base + 0] = (f0 >= 1.0f) ? 1.0f : 0.0f;   // tb+3 <= 123 < 125 always
    sout[base + 1] = (f1 >= 1.0f) ? 1.0f : 0.0f;
    sout[base + 2] = (f2 >= 1.0f) ? 1.0f : 0.0f;
    sout[base + 3] = (f3 >= 1.0f) ? 1.0f : 0.0f;
    if (tb + 4 < TT_) sout[base + 4] = (f4 >= 1.0f) ? 1.0f : 0.0f;
    if (tb + 5 < TT_) sout[base + 5] = (f5 >= 1.0f) ? 1.0f : 0.0f;
    if (tb + 6 < TT_) sout[base + 6] = (f6 >= 1.0f) ? 1.0f : 0.0f;
    if (tb + 7 < TT_) sout[base + 7] = (f7 >= 1.0f) ? 1.0f : 0.0f;
  }
}

// -------- l2f: out = spike(FIR(round32(W2 @ s1))), fused per (b, tile) -----
__global__ __launch_bounds__(256, 4) void l2f(
    const float* __restrict__ s1, const float* __restrict__ W2,
    float* __restrict__ outp)
{
  __shared__ float ss[HID_ * XSTR_];  // 16,384 B
  __shared__ float zf[OUT_ * ZSTR_];  // 18,240 B
  __shared__ float wf[OUT_ * HID_];   //  1,280 B
  __shared__ __align__(16) double eps_d[100];   // total ~36.7 KB

  const int tid  = threadIdx.x;
  const int b    = blockIdx.x >> 3;
  const int tile = blockIdx.x & 7;
  const int t0   = tile * TT_;

  init_eps_d(eps_d, tid);
  for (int idx = tid; idx < OUT_ * HID_; idx += 256)   // 320 > 256: strided
    wf[idx] = W2[idx];
  if (tid < OUT_ * 4)                              // zero zf pad cols 224..227
    zf[(tid >> 2) * ZSTR_ + 224 + (tid & 3)] = 0.0f;
  {
    const int  c   = tid;
    const int  tg  = t0 - 99 + c;
    const bool cok = (c < J_) && (tg >= 0);
    const float* sb = s1 + (size_t)b * HID_ * T_ + tg;
    float* dst = &ss[c];
#pragma unroll
    for (int r = 0; r < HID_; ++r)
      dst[r * XSTR_] = cok ? sb[r * T_] : 0.0f;
  }
  __syncthreads();

  const int p = tid >> 5;
  const int q = tid & 31;

#pragma unroll 1
  for (int pg = p; pg < 10; pg += 8) {   // p in {0,1} handles a second pair
    double m00=0,m01=0,m02=0,m03=0,m04=0,m05=0,m06=0,m07=0;
    double m10=0,m11=0,m12=0,m13=0,m14=0,m15=0,m16=0,m17=0;
    const int wb0 = (2*pg) * HID_;
    const int wb1 = wb0 + HID_;
#pragma unroll
    for (int i = 0; i < HID_; ++i) {
      const float* xr = &ss[i * XSTR_ + 2 * q];
      const double w0 = (double)wf[wb0 + i];
      const double w1 = (double)wf[wb1 + i];
      MMROW(xr, w0, w1)
    }
    ZSTORE_PAIR(&zf[(2*pg) * ZSTR_ + 2 * q])
  }
  __syncthreads();

#pragma unroll 1
  for (int task = tid; task < OUT_ * 16; task += 256) {
    const int h = task >> 4, q16 = task & 15;
    const float* zrow = &zf[h * ZSTR_ + 8 * q16];
    double u0=0,u1=0,u2=0,u3=0,u4=0,u5=0,u6=0,u7=0;
    FIR_BODY(zrow)
    const size_t base = ((size_t)b * OUT_ + h) * T_ + t0 + 8 * q16;
    const int tb = 8 * q16;
    const float f0=(float)u0, f1=(float)u1, f2=(float)u2, f3=(float)u3;
    const float f4=(float)u4, f5=(float)u5, f6=(float)u6, f7=(float)u7;
    outp[base + 0] = (f0 >= 1.0f) ? 1.0f : 0.0f;
    outp[base + 1] = (f1 >= 1.0f) ? 1.0f : 0.0f;
    outp[base + 2] = (f2 >= 1.0f) ? 1.0f : 0.0f;
    outp[base + 3] = (f3 >= 1.0f) ? 1.0f : 0.0f;
    if (tb + 4 < TT_) outp[base + 4] = (f4 >= 1.0f) ? 1.0f : 0.0f;
    if (tb + 5 < TT_) outp[base + 5] = (f5 >= 1.0f) ? 1.0f : 0.0f;
    if (tb + 6 < TT_) outp[base + 6] = (f6 >= 1.0f) ? 1.0f : 0.0f;
    if (tb + 7 < TT_) outp[base + 7] = (f7 >= 1.0f) ? 1.0f : 0.0f;
  }
}

extern "C" void kernel_launch(void* const* d_in, const int* in_sizes, int n_in,
                              void* d_out, int out_size, void* d_ws, size_t ws_size,
                              hipStream_t stream) {
  const float* x  = (const float*)d_in[0];
  const float* W1 = (const float*)d_in[1];
  const float* W2 = (const float*)d_in[2];
  float* outp = (float*)d_out;
  float* s1   = (float*)d_ws;          // [256,16,1000] f32 = 16.384 MB

  l1f<<<dim3(B_ * 8), dim3(256), 0, stream>>>(x,  W1, s1);
  l2f<<<dim3(B_ * 8), dim3(256), 0, stream>>>(s1, W2, outp);
}

// Round 13
// 115.395 us; speedup vs baseline: 7.1088x; 7.1088x over previous
//
#include <hip/hip_runtime.h>
#include <math.h>

// SLAYER MLP forward: spike(psp(W2 @ spike(psp(W1 @ x))))
// B=256, IN=78, HID=16, OUT=20, T=1000, K=100 (SRM alpha, tau=10)
//
// fp64 accumulation everywhere (absmax 0.0 rounds 0-12), fp32 rounding at
// reference materialization points (einsum outputs z1/z2, final u).
//
// Round-13: 3-kernel pipeline from proven parts. Round 12 proved
// launch_bounds caps => spills (VGPR 64/84, GBs of scratch traffic): NO caps
// anywhere. Full per-layer fusion (rounds 10-11) loses to the split pipeline
// (halo mm recompute + LDS-limited occupancy); the profitable fusion is
// fir1+mm2 ("fm"): a fir1 block holds all 16 h of s1 for its (b,tile) and
// mm2 is pointwise in t, so s1 never touches HBM (-45MB, -1 launch).
//  - mm1: round-9 version verbatim (chunked staging, issue-early regs)
//  - fm:  round-7 rolled FIR -> spikes into LDS sf[16][128] -> round-9 mm2
//         (MMROW2 lane layout, unroll-1 pg loop) -> z2 global
//  - fir_g: round-9 version, launched with 320 threads (20h x 16q = 1 pass)

#define B_     256
#define IN_    78
#define HID_   16
#define OUT_   20
#define T_     1000
#define TT_    125
#define J_     224              // TT + K - 1
#define ZSTR_  228              // fir LDS row stride (floats)
#define TC_    128              // mm1 t-chunk
#define MSTR_  132              // mm1 LDS row stride (floats)

// ---------------- FIR building blocks (named scalars only) ----------------
#define GRP(EP, A0,A1,A2,A3, B0,B1,B2,B3, C0,C1,C2) { \
  const double2 e01_ = *(const double2*)(EP); \
  const double2 e23_ = *(const double2*)((EP)+2); \
  u0 += e01_.x*(A3); u1 += e01_.x*(B0); u2 += e01_.x*(B1); u3 += e01_.x*(B2); \
  u4 += e01_.x*(B3); u5 += e01_.x*(C0); u6 += e01_.x*(C1); u7 += e01_.x*(C2); \
  u0 += e01_.y*(A2); u1 += e01_.y*(A3); u2 += e01_.y*(B0); u3 += e01_.y*(B1); \
  u4 += e01_.y*(B2); u5 += e01_.y*(B3); u6 += e01_.y*(C0); u7 += e01_.y*(C1); \
  u0 += e23_.x*(A1); u1 += e23_.x*(A2); u2 += e23_.x*(A3); u3 += e23_.x*(B0); \
  u4 += e23_.x*(B1); u5 += e23_.x*(B2); u6 += e23_.x*(B3); u7 += e23_.x*(C0); \
  u0 += e23_.y*(A0); u1 += e23_.y*(A1); u2 += e23_.y*(A2); u3 += e23_.y*(A3); \
  u4 += e23_.y*(B0); u5 += e23_.y*(B1); u6 += e23_.y*(B2); u7 += e23_.y*(B3); }

#define LOADF(X0,X1,X2,X3, P) { \
  const float4 lf_ = *(const float4*)(P); \
  X0 = (double)lf_.x; X1 = (double)lf_.y; X2 = (double)lf_.z; X3 = (double)lf_.w; }

// Rolled period-3 FIR over one zf row; expects eps_d, u0..u7 in scope.
#define FIR_BODY(ZROW) { \
  double A0,A1,A2,A3,B0,B1,B2,B3,C0,C1,C2,C3; \
  LOADF(A0,A1,A2,A3, (ZROW) + 96); \
  LOADF(B0,B1,B2,B3, (ZROW) + 100); \
  LOADF(C0,C1,C2,C3, (ZROW) + 104); \
  GRP(eps_d, A0,A1,A2,A3, B0,B1,B2,B3, C0,C1,C2) \
  const float*  zp_ = (ZROW) + 92; \
  const double* ep_ = eps_d + 4; \
  _Pragma("unroll 1") \
  for (int k_ = 0; k_ < 8; ++k_) { \
    LOADF(C0,C1,C2,C3, zp_); \
    GRP(ep_,     C0,C1,C2,C3, A0,A1,A2,A3, B0,B1,B2) \
    LOADF(B0,B1,B2,B3, zp_ - 4); \
    GRP(ep_ + 4, B0,B1,B2,B3, C0,C1,C2,C3, A0,A1,A2) \
    LOADF(A0,A1,A2,A3, zp_ - 8); \
    GRP(ep_ + 8, A0,A1,A2,A3, B0,B1,B2,B3, C0,C1,C2) \
    zp_ -= 12; ep_ += 12; \
  } }

__device__ __forceinline__ void init_eps_d(double* eps_d, int tid) {
  if (tid < 100) {
    float a = (float)tid / 10.0f;           // identical fp32 ops to reference
    float e = a * expf(1.0f - a);
    eps_d[tid] = (double)e;                 // exact widening
  }
}

// ---------------- mm building blocks --------------------------------------
// Per i-row: 2 float2 reads (t-pairs at stride 64) + 8 named-scalar dFMA.
#define MMROW2(XR, W0, W1) { \
  const float2 f0_ = *(const float2*)(XR); \
  const float2 f1_ = *(const float2*)((XR) + 64); \
  const double x0_=(double)f0_.x, x1_=(double)f0_.y; \
  const double x2_=(double)f1_.x, x3_=(double)f1_.y; \
  m00 += (W0)*x0_; m01 += (W0)*x1_; m02 += (W0)*x2_; m03 += (W0)*x3_; \
  m10 += (W1)*x0_; m11 += (W1)*x1_; m12 += (W1)*x2_; m13 += (W1)*x3_; }

#define STORE2(BASE, EOFF, MA, MB) \
  if (tb + (EOFF) < T_ - 1) \
    *(float2*)&zout[(BASE) + (size_t)(tb + (EOFF))] = \
        make_float2((float)(MA), (float)(MB));

// -------- mm1: z1[b,h,t] = sum_i W1[h,i] * x[b,i,t]  (round-9 verbatim) ----
// grid = 256 b * 8 t-chunks of 128; block 256 = 8 h-pairs x 32 lanes.
__global__ __launch_bounds__(256) void mm1(
    const float* __restrict__ x, const float* __restrict__ W1,
    float* __restrict__ zout)
{
  __shared__ float  xs[13 * MSTR_];   // 6,864 B
  __shared__ double wd[16 * 80];      // 10,240 B

  const int tid = threadIdx.x;
  const int b   = blockIdx.x >> 3;
  const int tc  = blockIdx.x & 7;
  const int tcb = tc * TC_;

  for (int idx = tid; idx < HID_ * IN_; idx += 256)
    wd[(idx / IN_) * 80 + (idx % IN_)] = (double)W1[idx];

  const int  c_  = tid & 127;
  const int  r0_ = tid >> 7;          // 0 or 1
  const int  tg_ = tcb + c_;
  const bool tok = (tg_ < T_);
  const bool t6  = tok && (r0_ == 0); // row 12 exists only for r0=0

  const int p = tid >> 5;
  const int q = tid & 31;

  double m00=0,m01=0,m02=0,m03=0,m10=0,m11=0,m12=0,m13=0;
  float g0,g1,g2,g3,g4,g5,g6;

#define ISSUE_MM1(CI) { \
    const float* xb_ = x + ((size_t)b * IN_ + (CI) * 13 + r0_) * T_ + tg_; \
    g0 = tok ? xb_[0]       : 0.0f; \
    g1 = tok ? xb_[2  * T_] : 0.0f; \
    g2 = tok ? xb_[4  * T_] : 0.0f; \
    g3 = tok ? xb_[6  * T_] : 0.0f; \
    g4 = tok ? xb_[8  * T_] : 0.0f; \
    g5 = tok ? xb_[10 * T_] : 0.0f; \
    g6 = t6  ? xb_[12 * T_] : 0.0f; }

  ISSUE_MM1(0)
  for (int ci = 0; ci < 6; ++ci) {
    __syncthreads();
    {
      float* dst = &xs[r0_ * MSTR_ + c_];
      dst[0]          = g0;  dst[2  * MSTR_] = g1;
      dst[4  * MSTR_] = g2;  dst[6  * MSTR_] = g3;
      dst[8  * MSTR_] = g4;  dst[10 * MSTR_] = g5;
      if (r0_ == 0) dst[12 * MSTR_] = g6;
    }
    __syncthreads();
    if (ci < 5) ISSUE_MM1(ci + 1)     // loads fly under the compute below
    const int wbase0 = (2*p)     * 80 + ci * 13;
    const int wbase1 = (2*p + 1) * 80 + ci * 13;
#pragma unroll
    for (int i = 0; i < 13; ++i) {
      const float* xr = &xs[i * MSTR_ + 2 * q];
      MMROW2(xr, wd[wbase0 + i], wd[wbase1 + i])
    }
  }

  const size_t r0s = ((size_t)b * HID_ + 2*p) * T_;
  const size_t r1s = r0s + T_;
  const int tb = tcb + 2 * q;
  STORE2(r0s,  0, m00, m01)  STORE2(r0s, 64, m02, m03)
  STORE2(r1s,  0, m10, m11)  STORE2(r1s, 64, m12, m13)
}

// -------- fm: z2 = round32(W2 @ spike(FIR(z1))), per (b, tile) -------------
// grid = 256 b * 8 tiles; block 256. Phase 1 = fir_g(R=16) writing spikes to
// LDS sf[16][128]; phase 2 = mm2 over this tile's 125 cols -> z2 global.
__global__ __launch_bounds__(256) void fm(
    const float* __restrict__ z1, const float* __restrict__ W2,
    float* __restrict__ z2)
{
  __shared__ float zf[HID_ * ZSTR_];  // 14,592 B
  __shared__ float sf[HID_ * 128];    //  8,192 B (spikes; cols >=125 unused)
  __shared__ float wf[OUT_ * HID_];   //  1,280 B
  __shared__ __align__(16) double eps_d[100];   // total ~24.9 KB

  const int tid  = threadIdx.x;
  const int b    = blockIdx.x >> 3;
  const int tile = blockIdx.x & 7;
  const int t0   = tile * TT_;

  init_eps_d(eps_d, tid);
  for (int idx = tid; idx < OUT_ * HID_; idx += 256)   // 320 > 256: strided
    wf[idx] = W2[idx];
  for (int idx = tid; idx < HID_ * ZSTR_; idx += 256) {
    const int cc = idx % ZSTR_;
    const int t  = t0 - 99 + cc;
    const int r  = idx / ZSTR_;
    zf[idx] = (cc < J_ && t >= 0) ? z1[((size_t)b * HID_ + r) * T_ + t] : 0.0f;
  }
  __syncthreads();

  { // FIR + spike -> sf: 16 h x 16 q16 = 256 tasks exactly
    const int h = tid >> 4, q16 = tid & 15;
    const float* zrow = &zf[h * ZSTR_ + 8 * q16];
    double u0=0,u1=0,u2=0,u3=0,u4=0,u5=0,u6=0,u7=0;
    FIR_BODY(zrow)
    float* sd = &sf[h * 128 + 8 * q16];
    sd[0] = ((float)u0 >= 1.0f) ? 1.0f : 0.0f;   // cols >=125 are garbage
    sd[1] = ((float)u1 >= 1.0f) ? 1.0f : 0.0f;   // (finite 0/1), never read
    sd[2] = ((float)u2 >= 1.0f) ? 1.0f : 0.0f;   // into a stored result
    sd[3] = ((float)u3 >= 1.0f) ? 1.0f : 0.0f;
    sd[4] = ((float)u4 >= 1.0f) ? 1.0f : 0.0f;
    sd[5] = ((float)u5 >= 1.0f) ? 1.0f : 0.0f;
    sd[6] = ((float)u6 >= 1.0f) ? 1.0f : 0.0f;
    sd[7] = ((float)u7 >= 1.0f) ? 1.0f : 0.0f;
  }
  __syncthreads();

  { // mm2: 8 p-slots x 32 lanes; pg-loop covers 10 o-pairs
    const int p = tid >> 5;
    const int q = tid & 31;
#pragma unroll 1
    for (int pg = p; pg < 10; pg += 8) {
      double m00=0,m01=0,m02=0,m03=0,m10=0,m11=0,m12=0,m13=0;
      const int wb0 = (2*pg)     * HID_;
      const int wb1 = (2*pg + 1) * HID_;
#pragma unroll
      for (int i = 0; i < HID_; ++i) {
        const float* xr = &sf[i * 128 + 2 * q];
        MMROW2(xr, (double)wf[wb0 + i], (double)wf[wb1 + i])
      }
      const size_t r0s = ((size_t)b * OUT_ + 2*pg) * T_ + t0;
      const size_t r1s = r0s + T_;
      const int c0 = 2 * q;            // 0..62: pair always valid (<125)
      *(float2*)&z2[r0s + c0] = make_float2((float)m00, (float)m01);
      *(float2*)&z2[r1s + c0] = make_float2((float)m10, (float)m11);
      const int c1 = 64 + 2 * q;       // 64..126: guard vs TT_=125
      if (c1 + 1 < TT_) {
        *(float2*)&z2[r0s + c1] = make_float2((float)m02, (float)m03);
        *(float2*)&z2[r1s + c1] = make_float2((float)m12, (float)m13);
      } else if (c1 < TT_) {           // c1 == 124: scalar
        z2[r0s + c1] = (float)m02;
        z2[r1s + c1] = (float)m12;
      }
    }
  }
}

// -------- fir_g: sout = spike(FIR(zin)), R rows -- launch with 320 thr -----
// tile_fixed < 0: grid = B*8; else grid = B, single tile (in-place safe when
// tiles launched in DESCENDING order; tile k reads t < 125(k+1)).
__global__ __launch_bounds__(320) void fir_g(
    const float* __restrict__ zin, float* __restrict__ sout,
    int R, int tile_fixed)
{
  __shared__ float zf[OUT_ * ZSTR_];   // 18,240 B (R<=20)
  __shared__ __align__(16) double eps_d[100];

  const int tid  = threadIdx.x;
  const int nthr = blockDim.x;
  const int b    = (tile_fixed >= 0) ? (int)blockIdx.x : (int)(blockIdx.x >> 3);
  const int tile = (tile_fixed >= 0) ? tile_fixed      : (int)(blockIdx.x & 7);
  const int t0   = tile * TT_;

  init_eps_d(eps_d, tid);
  for (int idx = tid; idx < R * ZSTR_; idx += nthr) {
    const int cc = idx % ZSTR_;
    const int t  = t0 - 99 + cc;
    const int r  = idx / ZSTR_;
    zf[idx] = (cc < J_ && t >= 0) ? zin[((size_t)b * R + r) * T_ + t] : 0.0f;
  }
  __syncthreads();

  for (int task = tid; task < R * 16; task += nthr) {
    const int h = task >> 4, q16 = task & 15;
    const float* zrow = &zf[h * ZSTR_ + 8 * q16];
    double u0=0,u1=0,u2=0,u3=0,u4=0,u5=0,u6=0,u7=0;
    FIR_BODY(zrow)
    const size_t base = ((size_t)b * R + h) * T_ + t0 + 8 * q16;
    const int tb = 8 * q16;
    const float f0=(float)u0, f1=(float)u1, f2=(float)u2, f3=(float)u3;
    const float f4=(float)u4, f5=(float)u5, f6=(float)u6, f7=(float)u7;
    sout[base + 0] = (f0 >= 1.0f) ? 1.0f : 0.0f;   // tb+3 <= 123 always valid
    sout[base + 1] = (f1 >= 1.0f) ? 1.0f : 0.0f;
    sout[base + 2] = (f2 >= 1.0f) ? 1.0f : 0.0f;
    sout[base + 3] = (f3 >= 1.0f) ? 1.0f : 0.0f;
    if (tb + 4 < TT_) sout[base + 4] = (f4 >= 1.0f) ? 1.0f : 0.0f;
    if (tb + 5 < TT_) sout[base + 5] = (f5 >= 1.0f) ? 1.0f : 0.0f;
    if (tb + 6 < TT_) sout[base + 6] = (f6 >= 1.0f) ? 1.0f : 0.0f;
    if (tb + 7 < TT_) sout[base + 7] = (f7 >= 1.0f) ? 1.0f : 0.0f;
  }
}

extern "C" void kernel_launch(void* const* d_in, const int* in_sizes, int n_in,
                              void* d_out, int out_size, void* d_ws, size_t ws_size,
                              hipStream_t stream) {
  const float* x  = (const float*)d_in[0];
  const float* W1 = (const float*)d_in[1];
  const float* W2 = (const float*)d_in[2];
  float* outp = (float*)d_out;
  float* base = (float*)d_ws;

  const size_t Z2E = (size_t)B_ * OUT_ * T_;   // 5.12M floats (20.5 MB)

  if (ws_size >= Z2E * sizeof(float)) {
    // z1 parks in d_out (16.4 MB <= 20.5 MB), z2 in ws; single fir2 launch.
    float* z1 = outp;
    float* z2 = base;
    mm1  <<<dim3(B_ * 8), dim3(256), 0, stream>>>(x,  W1, z1);
    fm   <<<dim3(B_ * 8), dim3(256), 0, stream>>>(z1, W2, z2);
    fir_g<<<dim3(B_ * 8), dim3(320), 0, stream>>>(z2, outp, OUT_, -1);
  } else {
    // ws >= 16.4 MB (proven rounds 10-12): z1 in ws, z2 in d_out,
    // fir2 in-place with descending tiles (proven race-free pattern).
    float* z1 = base;
    float* z2 = outp;
    mm1<<<dim3(B_ * 8), dim3(256), 0, stream>>>(x,  W1, z1);
    fm <<<dim3(B_ * 8), dim3(256), 0, stream>>>(z1, W2, z2);
    for (int k = 7; k >= 0; --k)
      fir_g<<<dim3(B_), dim3(320), 0, stream>>>(z2, z2, OUT_, k);
  }
}